// Round 1
// baseline (79.663 us; speedup 1.0000x reference)
//
#include <hip/hip_runtime.h>
#include <stdint.h>

#define N_SAMP 8192
#define D_DIM  512
#define P_DIM  1024
#define DT     0.1875f

typedef float f32x4 __attribute__((ext_vector_type(4)));
typedef short bf16x8 __attribute__((ext_vector_type(8)));
typedef unsigned short u16;

__device__ __forceinline__ u16 f2bf(float x){
    unsigned int u = __float_as_uint(x);
    return (u16)((u + 0x7FFFu + ((u >> 16) & 1u)) >> 16);
}

__device__ __forceinline__ void load_lds16(const void* g, void* l){
    __builtin_amdgcn_global_load_lds(
        (const __attribute__((address_space(1))) void*)(uintptr_t)g,
        (__attribute__((address_space(3))) void*)(uint32_t)(uintptr_t)l,
        16, 0, 0);
}

// ---- z (fp32) -> bf16, vectorized ----
__global__ __launch_bounds__(256) void k_zconv(const float4* __restrict__ z4,
                                               u16* __restrict__ zb){
    int i = blockIdx.x * 256 + threadIdx.x;       // N*D/4 = 1,048,576 threads
    float4 v = z4[i];
    ushort4 o;
    o.x = f2bf(v.x); o.y = f2bf(v.y); o.z = f2bf(v.z); o.w = f2bf(v.w);
    ((ushort4*)zb)[i] = o;
}

// ---- column inverse norms of A ----
__global__ __launch_bounds__(256) void k_norm(const float* __restrict__ A,
                                              float* __restrict__ inv){
    int p = blockIdx.x * 256 + threadIdx.x;       // 1024 threads
    float acc = 0.f;
    for (int d = 0; d < D_DIM; ++d){
        float v = A[(size_t)d * P_DIM + p];
        acc += v * v;
    }
    float nrm = fmaxf(sqrtf(acc), 1e-8f);
    inv[p] = 1.0f / nrm;
}

// ---- An^T (bf16) via LDS tile transpose: AnT[p][d] = A[d][p] * inv[p] ----
__global__ __launch_bounds__(256) void k_trans(const float* __restrict__ A,
                                               const float* __restrict__ inv,
                                               u16* __restrict__ AnT){
    __shared__ float tile[32][33];
    int p0 = (blockIdx.x & 31) * 32;
    int d0 = (blockIdx.x >> 5) * 32;
    int tx = threadIdx.x & 31, ty = threadIdx.x >> 5;   // 32 x 8
    #pragma unroll
    for (int j = 0; j < 4; ++j){
        int dd = ty + j * 8;
        tile[dd][tx] = A[(size_t)(d0 + dd) * P_DIM + p0 + tx];
    }
    __syncthreads();
    #pragma unroll
    for (int j = 0; j < 4; ++j){
        int pp = ty + j * 8;
        float s = inv[p0 + pp];
        AnT[(size_t)(p0 + pp) * D_DIM + d0 + tx] = f2bf(tile[tx][pp] * s);
    }
}

// ---- fused GEMM (128x128 bf16 MFMA) + ECF cos/sin accumulation ----
__global__ __launch_bounds__(256) void k_gemm_ecf(const u16* __restrict__ zb,
                                                  const u16* __restrict__ AnT,
                                                  float* __restrict__ partial){
    __shared__ uint4 smem4[2048];                 // 32 KiB
    u16* Abuf = (u16*)smem4;                      // [128][64] bf16
    u16* Bbuf = (u16*)smem4 + 8192;               // [128][64] bf16
    const int tid = threadIdx.x;
    const int bm = blockIdx.x >> 3, bn = blockIdx.x & 7;
    const int m0 = bm << 7, n0 = bn << 7;
    const int w = tid >> 6, lane = tid & 63;
    const int r = lane & 15, kg = lane >> 4;
    const int wm = (w >> 1) << 6, wn = (w & 1) << 6;

    // staging: per issue i, LDS bytes [i*4096 + tid*16] <- global row/col slice
    const int srow = tid >> 3;                    // 0..31
    const int kcol = (tid & 7) << 3;              // 0..56, step 8 elems (16B)
    const u16* gA = zb  + (size_t)(m0 + srow) * D_DIM + kcol;
    const u16* gB = AnT + (size_t)(n0 + srow) * D_DIM + kcol;
    char* lA = (char*)Abuf + (tid >> 6) * 1024;   // wave-uniform base
    char* lB = (char*)Bbuf + (tid >> 6) * 1024;

    f32x4 acc[4][4] = {};

    for (int kt = 0; kt < 8; ++kt){
        __syncthreads();
        #pragma unroll
        for (int i = 0; i < 4; ++i){
            load_lds16(gA + (size_t)i * 32 * D_DIM + kt * 64, lA + i * 4096);
            load_lds16(gB + (size_t)i * 32 * D_DIM + kt * 64, lB + i * 4096);
        }
        __syncthreads();
        #pragma unroll
        for (int ks = 0; ks < 2; ++ks){
            bf16x8 af[4], bfr[4];
            #pragma unroll
            for (int i = 0; i < 4; ++i)
                af[i] = *(const bf16x8*)&Abuf[(wm + i * 16 + r) * 64 + ks * 32 + kg * 8];
            #pragma unroll
            for (int j = 0; j < 4; ++j)
                bfr[j] = *(const bf16x8*)&Bbuf[(wn + j * 16 + r) * 64 + ks * 32 + kg * 8];
            #pragma unroll
            for (int i = 0; i < 4; ++i)
                #pragma unroll
                for (int j = 0; j < 4; ++j)
                    acc[i][j] = __builtin_amdgcn_mfma_f32_16x16x32_bf16(
                        af[i], bfr[j], acc[i][j], 0, 0, 0);
        }
    }

    // ---- epilogue: per-element Chebyshev cos/sin recurrence, reduce over rows ----
    __syncthreads();                              // all waves done reading LDS
    float* epil = (float*)smem4;                  // [4 waves][32 j][64 cols]
    #pragma unroll
    for (int jn = 0; jn < 4; ++jn){
        float cs[16], ss[16];
        #pragma unroll
        for (int k = 0; k < 16; ++k){ cs[k] = 0.f; ss[k] = 0.f; }
        #pragma unroll
        for (int i = 0; i < 4; ++i){
            #pragma unroll
            for (int q = 0; q < 4; ++q){
                float x = acc[i][jn][q] * DT;     // theta = proj * t1
                float s1, c1;
                __sincosf(x, &s1, &c1);
                float tc = c1 + c1;
                float ckm1 = 1.f, ck = c1, skm1 = 0.f, sk = s1;
                cs[0] += c1; ss[0] += s1;
                #pragma unroll
                for (int k = 2; k <= 16; ++k){
                    float cn = fmaf(tc, ck, -ckm1);
                    float sn = fmaf(tc, sk, -skm1);
                    cs[k - 1] += cn; ss[k - 1] += sn;
                    ckm1 = ck; ck = cn; skm1 = sk; sk = sn;
                }
            }
        }
        // sum over the 4 row-groups (lanes l, l^16, l^32, l^48 share a column)
        #pragma unroll
        for (int k = 0; k < 16; ++k){
            cs[k] += __shfl_xor(cs[k], 16); cs[k] += __shfl_xor(cs[k], 32);
            ss[k] += __shfl_xor(ss[k], 16); ss[k] += __shfl_xor(ss[k], 32);
        }
        if (lane < 16){
            const int cl = jn * 16 + lane;
            #pragma unroll
            for (int k = 0; k < 16; ++k){
                epil[(w * 32 + k)      * 64 + cl] = cs[k];
                epil[(w * 32 + 16 + k) * 64 + cl] = ss[k];
            }
        }
    }
    __syncthreads();
    // coalesced write: partial[slot][j][p], slot = bm*2 + rowhalf
    for (int f0 = 0; f0 < 8192; f0 += 256){
        int f = f0 + tid;
        int cl = f & 63, j = (f >> 6) & 31, ww = f >> 11;
        int slot = bm * 2 + (ww >> 1);
        int p = n0 + ((ww & 1) << 6) + cl;
        partial[((size_t)slot * 32 + j) * 1024 + p] = epil[f];
    }
}

// ---- reduce partials over 128 slots, apply (cm-phi)^2 + sm^2 weighted ----
__global__ __launch_bounds__(256) void k_reduce(const float* __restrict__ partial,
                                                float* __restrict__ bpart){
    const int tid = threadIdx.x;
    const int idx = blockIdx.x * 256 + tid;       // 0..32767
    const int p = idx & 1023, j = idx >> 10;      // j: 0..15 cos(k=j+1), 16..31 sin
    float s = 0.f;
    for (int slot = 0; slot < 128; ++slot)
        s += partial[((size_t)slot * 32 + j) * 1024 + p];
    const int k = (j & 15) + 1;
    float tk = (float)k * DT;
    float phik = expf(-0.5f * tk * tk);
    float wk = ((k == 16) ? DT : 2.f * DT) * phik;
    float mean = s * (1.f / (float)N_SAMP);
    float diff = (j < 16) ? (mean - phik) : mean;
    float term = diff * diff * wk;
    #pragma unroll
    for (int o = 32; o > 0; o >>= 1) term += __shfl_xor(term, o);
    __shared__ float red[4];
    if ((tid & 63) == 0) red[tid >> 6] = term;
    __syncthreads();
    if (tid == 0) bpart[blockIdx.x] = red[0] + red[1] + red[2] + red[3];
}

__global__ void k_final(const float* __restrict__ bpart, float* __restrict__ out){
    int t = threadIdx.x;                          // 64 threads
    float v = bpart[t] + bpart[t + 64];
    #pragma unroll
    for (int o = 32; o > 0; o >>= 1) v += __shfl_xor(v, o);
    if (t == 0) out[0] = v * ((float)N_SAMP / (float)P_DIM);
}

extern "C" void kernel_launch(void* const* d_in, const int* in_sizes, int n_in,
                              void* d_out, int out_size, void* d_ws, size_t ws_size,
                              hipStream_t stream){
    const float* z = (const float*)d_in[0];
    const float* A = (const float*)d_in[1];
    char* ws = (char*)d_ws;
    // ws layout (bytes):
    float* inv     = (float*)(ws);                // 4 KiB
    float* bpart   = (float*)(ws + 4096);         // 512 B (128 f32)
    u16*   AnT     = (u16*)  (ws + 8192);         // 1 MiB  [1024][512] bf16
    u16*   zb      = (u16*)  (ws + 1056768);      // 8 MiB  [8192][512] bf16
    float* partial = (float*)(ws + 9445376);      // 16 MiB [128][32][1024] f32
    float* out     = (float*)d_out;

    hipLaunchKernelGGL(k_zconv,    dim3(4096), dim3(256), 0, stream,
                       (const float4*)z, zb);
    hipLaunchKernelGGL(k_norm,     dim3(4),    dim3(256), 0, stream, A, inv);
    hipLaunchKernelGGL(k_trans,    dim3(512),  dim3(256), 0, stream, A, inv, AnT);
    hipLaunchKernelGGL(k_gemm_ecf, dim3(512),  dim3(256), 0, stream, zb, AnT, partial);
    hipLaunchKernelGGL(k_reduce,   dim3(128),  dim3(256), 0, stream, partial, bpart);
    hipLaunchKernelGGL(k_final,    dim3(1),    dim3(64),  0, stream, bpart, out);
}

// Round 2
// 56.827 us; speedup vs baseline: 1.4018x; 1.4018x over previous
//
#include <hip/hip_runtime.h>
#include <stdint.h>

#define N_SAMP 8192
#define D_DIM  512
#define P_DIM  1024
#define DT     0.1875f

typedef float f32x4 __attribute__((ext_vector_type(4)));
typedef short bf16x8 __attribute__((ext_vector_type(8)));
typedef unsigned short u16;

__device__ __forceinline__ u16 f2bf(float x){
    unsigned int u = __float_as_uint(x);
    return (u16)((u + 0x7FFFu + ((u >> 16) & 1u)) >> 16);
}

__device__ __forceinline__ void load_lds16(const void* g, void* l){
    __builtin_amdgcn_global_load_lds(
        (const __attribute__((address_space(1))) void*)(uintptr_t)g,
        (__attribute__((address_space(3))) void*)(uint32_t)(uintptr_t)l,
        16, 0, 0);
}

// ---- z (fp32) -> bf16, vectorized ----
__global__ __launch_bounds__(256) void k_zconv(const float4* __restrict__ z4,
                                               u16* __restrict__ zb){
    int i = blockIdx.x * 256 + threadIdx.x;       // N*D/4 = 1,048,576 threads
    float4 v = z4[i];
    ushort4 o;
    o.x = f2bf(v.x); o.y = f2bf(v.y); o.z = f2bf(v.z); o.w = f2bf(v.w);
    ((ushort4*)zb)[i] = o;
}

// ---- column inverse norms of A: 32 blocks, float4 along p ----
__global__ __launch_bounds__(256) void k_norm(const float* __restrict__ A,
                                              float* __restrict__ inv){
    const float4* A4 = (const float4*)A;          // [512][256] float4
    const int tid = threadIdx.x;
    const int q = tid & 7;                        // p-quad within block (8 quads = 32 p)
    const int g = tid >> 3;                       // d-group 0..31 (16 rows each)
    const int c = (blockIdx.x << 3) + q;          // float4 column index
    float sx = 0.f, sy = 0.f, sz = 0.f, sw = 0.f;
    #pragma unroll 4
    for (int dd = 0; dd < 16; ++dd){
        float4 v = A4[(size_t)(g * 16 + dd) * 256 + c];
        sx += v.x * v.x; sy += v.y * v.y; sz += v.z * v.z; sw += v.w * v.w;
    }
    __shared__ float red[8][32][4];
    red[q][g][0] = sx; red[q][g][1] = sy; red[q][g][2] = sz; red[q][g][3] = sw;
    __syncthreads();
    if (tid < 32){                                // 8 quads x 4 components
        int qq = tid >> 2, comp = tid & 3;
        float s = 0.f;
        #pragma unroll
        for (int gg = 0; gg < 32; ++gg) s += red[qq][gg][comp];
        float nrm = fmaxf(sqrtf(s), 1e-8f);
        inv[(c - q + qq) * 4 + comp] = 1.0f / nrm;   // p = 4*(block*8+qq)+comp
    }
}

// ---- An^T (bf16) via LDS tile transpose: AnT[p][d] = A[d][p] * inv[p] ----
__global__ __launch_bounds__(256) void k_trans(const float* __restrict__ A,
                                               const float* __restrict__ inv,
                                               u16* __restrict__ AnT){
    __shared__ float tile[32][33];
    int p0 = (blockIdx.x & 31) * 32;
    int d0 = (blockIdx.x >> 5) * 32;
    int tx = threadIdx.x & 31, ty = threadIdx.x >> 5;   // 32 x 8
    #pragma unroll
    for (int j = 0; j < 4; ++j){
        int dd = ty + j * 8;
        tile[dd][tx] = A[(size_t)(d0 + dd) * P_DIM + p0 + tx];
    }
    __syncthreads();
    #pragma unroll
    for (int j = 0; j < 4; ++j){
        int pp = ty + j * 8;
        float s = inv[p0 + pp];
        AnT[(size_t)(p0 + pp) * D_DIM + d0 + tx] = f2bf(tile[tx][pp] * s);
    }
}

// ---- fused GEMM (128x128 bf16 MFMA, double-buffered staging) + ECF ----
__global__ __launch_bounds__(256) void k_gemm_ecf(const u16* __restrict__ zb,
                                                  const u16* __restrict__ AnT,
                                                  float* __restrict__ partial){
    __shared__ uint4 smem4[4096];                 // 64 KiB: 2 x (A 16K + B 16K)
    const int tid = threadIdx.x;
    const int bm = blockIdx.x >> 3, bn = blockIdx.x & 7;
    const int m0 = bm << 7, n0 = bn << 7;
    const int w = tid >> 6, lane = tid & 63;
    const int r = lane & 15, kg = lane >> 4;
    const int wm = (w >> 1) << 6, wn = (w & 1) << 6;

    // staging: per issue i, LDS bytes [buf + i*4096 + tid*16]
    const int srow = tid >> 3;                    // 0..31
    const int kcol = (tid & 7) << 3;              // 0..56, step 8 elems (16B)
    const u16* gA = zb  + (size_t)(m0 + srow) * D_DIM + kcol;
    const u16* gB = AnT + (size_t)(n0 + srow) * D_DIM + kcol;
    char* lbase = (char*)smem4 + w * 1024;        // wave-uniform base

    f32x4 acc[4][4] = {};

    // prologue: stage tile 0 into buf0
    #pragma unroll
    for (int i = 0; i < 4; ++i){
        load_lds16(gA + (size_t)i * 32 * D_DIM, lbase + i * 4096);
        load_lds16(gB + (size_t)i * 32 * D_DIM, lbase + 16384 + i * 4096);
    }

    for (int kt = 0; kt < 8; ++kt){
        const int cur = kt & 1;
        __syncthreads();                          // vmcnt(0)+lgkmcnt(0)+barrier: cur tile ready, prev reads done
        if (kt < 7){                              // issue next tile; latency hides under MFMA below
            char* la = lbase + ((kt + 1) & 1) * 32768;
            #pragma unroll
            for (int i = 0; i < 4; ++i){
                load_lds16(gA + (size_t)i * 32 * D_DIM + (kt + 1) * 64, la + i * 4096);
                load_lds16(gB + (size_t)i * 32 * D_DIM + (kt + 1) * 64, la + 16384 + i * 4096);
            }
        }
        const u16* Ab = (const u16*)smem4 + cur * 16384;
        const u16* Bb = Ab + 8192;
        #pragma unroll
        for (int ks = 0; ks < 2; ++ks){
            bf16x8 af[4], bfr[4];
            #pragma unroll
            for (int i = 0; i < 4; ++i)
                af[i] = *(const bf16x8*)&Ab[(wm + i * 16 + r) * 64 + ks * 32 + kg * 8];
            #pragma unroll
            for (int j = 0; j < 4; ++j)
                bfr[j] = *(const bf16x8*)&Bb[(wn + j * 16 + r) * 64 + ks * 32 + kg * 8];
            #pragma unroll
            for (int i = 0; i < 4; ++i)
                #pragma unroll
                for (int j = 0; j < 4; ++j)
                    acc[i][j] = __builtin_amdgcn_mfma_f32_16x16x32_bf16(
                        af[i], bfr[j], acc[i][j], 0, 0, 0);
        }
    }

    // ---- epilogue: Chebyshev cos/sin recurrence, reduce over rows ----
    __syncthreads();                              // all waves done with LDS tiles
    float* epil = (float*)smem4;                  // [4 waves][32 j][64 cols] = 32 KiB
    #pragma unroll
    for (int jn = 0; jn < 4; ++jn){
        float cs[16], ss[16];
        #pragma unroll
        for (int k = 0; k < 16; ++k){ cs[k] = 0.f; ss[k] = 0.f; }
        #pragma unroll
        for (int i = 0; i < 4; ++i){
            #pragma unroll
            for (int q = 0; q < 4; ++q){
                float x = acc[i][jn][q] * DT;     // theta = proj * t1
                float s1, c1;
                __sincosf(x, &s1, &c1);
                float tc = c1 + c1;
                float ckm1 = 1.f, ck = c1, skm1 = 0.f, sk = s1;
                cs[0] += c1; ss[0] += s1;
                #pragma unroll
                for (int k = 2; k <= 16; ++k){
                    float cn = fmaf(tc, ck, -ckm1);
                    float sn = fmaf(tc, sk, -skm1);
                    cs[k - 1] += cn; ss[k - 1] += sn;
                    ckm1 = ck; ck = cn; skm1 = sk; sk = sn;
                }
            }
        }
        // lanes l, l^16, l^32, l^48 share a column
        #pragma unroll
        for (int k = 0; k < 16; ++k){
            cs[k] += __shfl_xor(cs[k], 16); cs[k] += __shfl_xor(cs[k], 32);
            ss[k] += __shfl_xor(ss[k], 16); ss[k] += __shfl_xor(ss[k], 32);
        }
        if (lane < 16){
            const int cl = jn * 16 + lane;
            #pragma unroll
            for (int k = 0; k < 16; ++k){
                epil[(w * 32 + k)      * 64 + cl] = cs[k];
                epil[(w * 32 + 16 + k) * 64 + cl] = ss[k];
            }
        }
    }
    __syncthreads();
    // fold the two row-halves (w and w+2), write partial[bm][j][p] coalesced
    for (int f0 = 0; f0 < 4096; f0 += 256){
        int f = f0 + tid;
        int cl = f & 127, j = f >> 7;             // p-in-tile, j-index
        int whi = cl >> 6, cll = cl & 63;
        float v = epil[(whi * 32 + j) * 64 + cll] +
                  epil[((whi + 2) * 32 + j) * 64 + cll];
        partial[((size_t)bm * 32 + j) * 1024 + n0 + cl] = v;
    }
}

// ---- reduce partials over 64 slots, apply (cm-phi)^2 + sm^2 weighted ----
__global__ __launch_bounds__(256) void k_reduce(const float* __restrict__ partial,
                                                float* __restrict__ bpart){
    const int tid = threadIdx.x;
    const int idx = blockIdx.x * 256 + tid;       // 0..32767
    const int p = idx & 1023, j = idx >> 10;      // j: 0..15 cos(k=j+1), 16..31 sin
    float s = 0.f;
    #pragma unroll 4
    for (int slot = 0; slot < 64; ++slot)
        s += partial[((size_t)slot * 32 + j) * 1024 + p];
    const int k = (j & 15) + 1;
    float tk = (float)k * DT;
    float phik = expf(-0.5f * tk * tk);
    float wk = ((k == 16) ? DT : 2.f * DT) * phik;
    float mean = s * (1.f / (float)N_SAMP);
    float diff = (j < 16) ? (mean - phik) : mean;
    float term = diff * diff * wk;
    #pragma unroll
    for (int o = 32; o > 0; o >>= 1) term += __shfl_xor(term, o);
    __shared__ float red[4];
    if ((tid & 63) == 0) red[tid >> 6] = term;
    __syncthreads();
    if (tid == 0) bpart[blockIdx.x] = red[0] + red[1] + red[2] + red[3];
}

__global__ void k_final(const float* __restrict__ bpart, float* __restrict__ out){
    int t = threadIdx.x;                          // 64 threads
    float v = bpart[t] + bpart[t + 64];
    #pragma unroll
    for (int o = 32; o > 0; o >>= 1) v += __shfl_xor(v, o);
    if (t == 0) out[0] = v * ((float)N_SAMP / (float)P_DIM);
}

extern "C" void kernel_launch(void* const* d_in, const int* in_sizes, int n_in,
                              void* d_out, int out_size, void* d_ws, size_t ws_size,
                              hipStream_t stream){
    const float* z = (const float*)d_in[0];
    const float* A = (const float*)d_in[1];
    char* ws = (char*)d_ws;
    // ws layout (bytes):
    float* inv     = (float*)(ws);                // 4 KiB
    float* bpart   = (float*)(ws + 4096);         // 512 B (128 f32)
    u16*   AnT     = (u16*)  (ws + 8192);         // 1 MiB  [1024][512] bf16
    u16*   zb      = (u16*)  (ws + 1056768);      // 8 MiB  [8192][512] bf16
    float* partial = (float*)(ws + 9445376);      // 8 MiB  [64][32][1024] f32
    float* out     = (float*)d_out;

    hipLaunchKernelGGL(k_zconv,    dim3(4096), dim3(256), 0, stream,
                       (const float4*)z, zb);
    hipLaunchKernelGGL(k_norm,     dim3(32),   dim3(256), 0, stream, A, inv);
    hipLaunchKernelGGL(k_trans,    dim3(512),  dim3(256), 0, stream, A, inv, AnT);
    hipLaunchKernelGGL(k_gemm_ecf, dim3(512),  dim3(256), 0, stream, zb, AnT, partial);
    hipLaunchKernelGGL(k_reduce,   dim3(128),  dim3(256), 0, stream, partial, bpart);
    hipLaunchKernelGGL(k_final,    dim3(1),    dim3(64),  0, stream, bpart, out);
}

// Round 3
// 49.755 us; speedup vs baseline: 1.6011x; 1.1421x over previous
//
#include <hip/hip_runtime.h>
#include <stdint.h>

#define N_SAMP 8192
#define D_DIM  512
#define P_DIM  1024
#define DT     0.1875f

typedef float f32x4 __attribute__((ext_vector_type(4)));
typedef float f32x2 __attribute__((ext_vector_type(2)));
typedef short bf16x8 __attribute__((ext_vector_type(8)));
typedef unsigned short u16;

__device__ __forceinline__ u16 f2bf(float x){
    unsigned int u = __float_as_uint(x);
    return (u16)((u + 0x7FFFu + ((u >> 16) & 1u)) >> 16);
}

__device__ __forceinline__ void load_lds16(const void* g, void* l){
    __builtin_amdgcn_global_load_lds(
        (const __attribute__((address_space(1))) void*)(uintptr_t)g,
        (__attribute__((address_space(3))) void*)(uint32_t)(uintptr_t)l,
        16, 0, 0);
}

// ---- z (fp32) -> bf16, vectorized; also zero-inits d_out for the atomic path ----
__global__ __launch_bounds__(256) void k_zconv(const float4* __restrict__ z4,
                                               u16* __restrict__ zb,
                                               float* __restrict__ out){
    int i = blockIdx.x * 256 + threadIdx.x;       // N*D/4 = 1,048,576 threads
    if (i == 0) out[0] = 0.f;                     // stream-ordered before k_reduce
    float4 v = z4[i];
    ushort4 o;
    o.x = f2bf(v.x); o.y = f2bf(v.y); o.z = f2bf(v.z); o.w = f2bf(v.w);
    ((ushort4*)zb)[i] = o;
}

// ---- column inverse norms of A: 32 blocks, float4 along p ----
__global__ __launch_bounds__(256) void k_norm(const float* __restrict__ A,
                                              float* __restrict__ inv){
    const float4* A4 = (const float4*)A;          // [512][256] float4
    const int tid = threadIdx.x;
    const int q = tid & 7;                        // p-quad within block (8 quads = 32 p)
    const int g = tid >> 3;                       // d-group 0..31 (16 rows each)
    const int c = (blockIdx.x << 3) + q;          // float4 column index
    float sx = 0.f, sy = 0.f, sz = 0.f, sw = 0.f;
    #pragma unroll 4
    for (int dd = 0; dd < 16; ++dd){
        float4 v = A4[(size_t)(g * 16 + dd) * 256 + c];
        sx += v.x * v.x; sy += v.y * v.y; sz += v.z * v.z; sw += v.w * v.w;
    }
    __shared__ float red[8][32][4];
    red[q][g][0] = sx; red[q][g][1] = sy; red[q][g][2] = sz; red[q][g][3] = sw;
    __syncthreads();
    if (tid < 32){                                // 8 quads x 4 components
        int qq = tid >> 2, comp = tid & 3;
        float s = 0.f;
        #pragma unroll
        for (int gg = 0; gg < 32; ++gg) s += red[qq][gg][comp];
        float nrm = fmaxf(sqrtf(s), 1e-8f);
        inv[(c - q + qq) * 4 + comp] = 1.0f / nrm;   // p = 4*(block*8+qq)+comp
    }
}

// ---- An^T (bf16) via LDS tile transpose: AnT[p][d] = A[d][p] * inv[p] ----
__global__ __launch_bounds__(256) void k_trans(const float* __restrict__ A,
                                               const float* __restrict__ inv,
                                               u16* __restrict__ AnT){
    __shared__ float tile[32][33];
    int p0 = (blockIdx.x & 31) * 32;
    int d0 = (blockIdx.x >> 5) * 32;
    int tx = threadIdx.x & 31, ty = threadIdx.x >> 5;   // 32 x 8
    #pragma unroll
    for (int j = 0; j < 4; ++j){
        int dd = ty + j * 8;
        tile[dd][tx] = A[(size_t)(d0 + dd) * P_DIM + p0 + tx];
    }
    __syncthreads();
    #pragma unroll
    for (int j = 0; j < 4; ++j){
        int pp = ty + j * 8;
        float s = inv[p0 + pp];
        AnT[(size_t)(p0 + pp) * D_DIM + d0 + tx] = f2bf(tile[tx][pp] * s);
    }
}

// ---- fused GEMM (128x128 bf16 MFMA, dbuf staging, XOR-swizzled LDS) + ECF ----
// LDS granule swizzle (16B granules, 8 per 128B row): slot g holds global
// granule g ^ (row&7). Applied on the global SOURCE address (LDS dest stays
// linear for global_load_lds) and identically on the ds_read offset.
__global__ __launch_bounds__(256) void k_gemm_ecf(const u16* __restrict__ zb,
                                                  const u16* __restrict__ AnT,
                                                  float* __restrict__ partial){
    __shared__ uint4 smem4[4096];                 // 64 KiB: 2 x (A 16K + B 16K)
    const int tid = threadIdx.x;
    const int bm = blockIdx.x >> 3, bn = blockIdx.x & 7;
    const int m0 = bm << 7, n0 = bn << 7;
    const int w = tid >> 6, lane = tid & 63;
    const int r = lane & 15, kg = lane >> 4;
    const int wm = (w >> 1) << 6, wn = (w & 1) << 6;

    // staging: thread t writes LDS granule (row=t>>3, g=t&7) linearly; source
    // global granule is (t&7) ^ (row&7)  -> inverse of the read swizzle.
    const int srow = tid >> 3;                    // 0..31
    const int gsw  = ((tid & 7) ^ (srow & 7)) << 3;   // elements
    const u16* gA = zb  + (size_t)(m0 + srow) * D_DIM + gsw;
    const u16* gB = AnT + (size_t)(n0 + srow) * D_DIM + gsw;
    char* lbase = (char*)smem4 + w * 1024;        // wave-uniform base

    f32x4 acc[4][4] = {};

    // prologue: stage tile 0 into buf0
    #pragma unroll
    for (int i = 0; i < 4; ++i){
        load_lds16(gA + (size_t)i * 32 * D_DIM, lbase + i * 4096);
        load_lds16(gB + (size_t)i * 32 * D_DIM, lbase + 16384 + i * 4096);
    }

    for (int kt = 0; kt < 8; ++kt){
        const int cur = kt & 1;
        __syncthreads();                          // cur tile ready, prev reads done
        if (kt < 7){                              // issue next tile under the MFMAs
            char* la = lbase + ((kt + 1) & 1) * 32768;
            #pragma unroll
            for (int i = 0; i < 4; ++i){
                load_lds16(gA + (size_t)i * 32 * D_DIM + (kt + 1) * 64, la + i * 4096);
                load_lds16(gB + (size_t)i * 32 * D_DIM + (kt + 1) * 64, la + 16384 + i * 4096);
            }
        }
        const u16* Ab = (const u16*)smem4 + cur * 16384;
        const u16* Bb = Ab + 8192;
        #pragma unroll
        for (int ks = 0; ks < 2; ++ks){
            bf16x8 af[4], bfr[4];
            #pragma unroll
            for (int i = 0; i < 4; ++i)
                af[i] = *(const bf16x8*)&Ab[(wm + i * 16 + r) * 64 +
                                            (((ks * 4 + kg) ^ (r & 7)) << 3)];
            #pragma unroll
            for (int j = 0; j < 4; ++j)
                bfr[j] = *(const bf16x8*)&Bb[(wn + j * 16 + r) * 64 +
                                             (((ks * 4 + kg) ^ (r & 7)) << 3)];
            #pragma unroll
            for (int i = 0; i < 4; ++i)
                #pragma unroll
                for (int j = 0; j < 4; ++j)
                    acc[i][j] = __builtin_amdgcn_mfma_f32_16x16x32_bf16(
                        af[i], bfr[j], acc[i][j], 0, 0, 0);
        }
    }

    // ---- epilogue: packed (cos,sin) Chebyshev recurrence, reduce over rows ----
    __syncthreads();                              // all waves done with LDS tiles
    float* epil = (float*)smem4;                  // [4 waves][32 j][64 cols] = 32 KiB
    #pragma unroll
    for (int jn = 0; jn < 4; ++jn){
        f32x2 sum[16];
        #pragma unroll
        for (int k = 0; k < 16; ++k) sum[k] = (f32x2){0.f, 0.f};
        #pragma unroll
        for (int i = 0; i < 4; ++i){
            #pragma unroll
            for (int q = 0; q < 4; ++q){
                float x = acc[i][jn][q] * DT;     // theta = proj * t1
                float c1 = __cosf(x), s1 = __sinf(x);
                float tc = c1 + c1;
                f32x2 prev = {1.f, 0.f};
                f32x2 curv = {c1, s1};
                sum[0] += curv;
                #pragma unroll
                for (int k = 2; k <= 16; ++k){
                    f32x2 nxt = tc * curv - prev; // v_pk_fma_f32 candidate
                    sum[k - 1] += nxt;
                    prev = curv; curv = nxt;
                }
            }
        }
        // lanes l, l^16, l^32, l^48 share a column
        #pragma unroll
        for (int k = 0; k < 16; ++k){
            f32x2 o;
            o.x = __shfl_xor(sum[k].x, 16); o.y = __shfl_xor(sum[k].y, 16);
            sum[k] += o;
            o.x = __shfl_xor(sum[k].x, 32); o.y = __shfl_xor(sum[k].y, 32);
            sum[k] += o;
        }
        if (lane < 16){
            const int cl = jn * 16 + lane;
            #pragma unroll
            for (int k = 0; k < 16; ++k){
                epil[(w * 32 + k)      * 64 + cl] = sum[k].x;
                epil[(w * 32 + 16 + k) * 64 + cl] = sum[k].y;
            }
        }
    }
    __syncthreads();
    // fold the two row-halves (w and w+2), write partial[bm][j][p] coalesced
    for (int f0 = 0; f0 < 4096; f0 += 256){
        int f = f0 + tid;
        int cl = f & 127, j = f >> 7;             // p-in-tile, j-index
        int whi = cl >> 6, cll = cl & 63;
        float v = epil[(whi * 32 + j) * 64 + cll] +
                  epil[((whi + 2) * 32 + j) * 64 + cll];
        partial[((size_t)bm * 32 + j) * 1024 + n0 + cl] = v;
    }
}

// ---- reduce partials over 64 slots, weighted, atomicAdd to scalar out ----
__global__ __launch_bounds__(256) void k_reduce(const float* __restrict__ partial,
                                                float* __restrict__ out){
    const int tid = threadIdx.x;
    const int idx = blockIdx.x * 256 + tid;       // 0..32767
    const int p = idx & 1023, j = idx >> 10;      // j: 0..15 cos(k=j+1), 16..31 sin
    float s = 0.f;
    #pragma unroll 4
    for (int slot = 0; slot < 64; ++slot)
        s += partial[((size_t)slot * 32 + j) * 1024 + p];
    const int k = (j & 15) + 1;
    float tk = (float)k * DT;
    float phik = expf(-0.5f * tk * tk);
    float wk = ((k == 16) ? DT : 2.f * DT) * phik;
    float mean = s * (1.f / (float)N_SAMP);
    float diff = (j < 16) ? (mean - phik) : mean;
    float term = diff * diff * wk;
    #pragma unroll
    for (int o = 32; o > 0; o >>= 1) term += __shfl_xor(term, o);
    __shared__ float red[4];
    if ((tid & 63) == 0) red[tid >> 6] = term;
    __syncthreads();
    if (tid == 0)
        atomicAdd(out, (red[0] + red[1] + red[2] + red[3]) *
                       ((float)N_SAMP / (float)P_DIM));
}

extern "C" void kernel_launch(void* const* d_in, const int* in_sizes, int n_in,
                              void* d_out, int out_size, void* d_ws, size_t ws_size,
                              hipStream_t stream){
    const float* z = (const float*)d_in[0];
    const float* A = (const float*)d_in[1];
    char* ws = (char*)d_ws;
    // ws layout (bytes):
    float* inv     = (float*)(ws);                // 4 KiB
    u16*   AnT     = (u16*)  (ws + 8192);         // 1 MiB  [1024][512] bf16
    u16*   zb      = (u16*)  (ws + 1056768);      // 8 MiB  [8192][512] bf16
    float* partial = (float*)(ws + 9445376);      // 8 MiB  [64][32][1024] f32
    float* out     = (float*)d_out;

    hipLaunchKernelGGL(k_zconv,    dim3(4096), dim3(256), 0, stream,
                       (const float4*)z, zb, out);
    hipLaunchKernelGGL(k_norm,     dim3(32),   dim3(256), 0, stream, A, inv);
    hipLaunchKernelGGL(k_trans,    dim3(512),  dim3(256), 0, stream, A, inv, AnT);
    hipLaunchKernelGGL(k_gemm_ecf, dim3(512),  dim3(256), 0, stream, zb, AnT, partial);
    hipLaunchKernelGGL(k_reduce,   dim3(128),  dim3(256), 0, stream, partial, out);
}